// Round 12
// baseline (178.020 us; speedup 1.0000x reference)
//
#include <hip/hip_runtime.h>

#define TOPK_K 13
#define KPAD 16
#define PCAP 384   // > max in-box anchors per gt (<=336 for 128px box)

// ---- shared math helpers: every am/IoU value in all kernels flows through
// these, so threshold comparisons and argmax are bit-exact vs each other. ----

__device__ __forceinline__ float iou_clip(const float4 g, const float4 p) {
    float ix1 = fmaxf(g.x, p.x), iy1 = fmaxf(g.y, p.y);
    float ix2 = fminf(g.z, p.z), iy2 = fminf(g.w, p.w);
    float iw = fmaxf(ix2 - ix1, 0.f);
    float ih = fmaxf(iy2 - iy1, 0.f);
    float inter = iw * ih;
    float a1 = (g.z - g.x) * (g.w - g.y);
    float a2 = (p.z - p.x) * (p.w - p.y);
    float iou = inter / (a1 + a2 - inter + 1e-7f);
    return fmaxf(iou, 0.f);
}

__device__ __forceinline__ float in_box(float ax, float ay, const float4 g) {
    float m = fminf(fminf(ax - g.x, ay - g.y), fminf(g.z - ax, g.w - ay));
    return (m > 0.f) ? 1.f : 0.f;
}

__device__ __forceinline__ float align_metric_f(float sqs, float iou, float valid) {
    float p2 = iou * iou;
    float p6 = p2 * p2 * p2;
    return sqs * p6 * valid;
}

// anchor index -> center coords (bit-exact vs reference (arange+0.5)*s)
__device__ __forceinline__ void anc_xy(int i, float& ax, float& ay) {
    int lvl = (i < 6400) ? 0 : (i < 8000 ? 1 : 2);
    int n   = (lvl == 0) ? 80 : (lvl == 1 ? 40 : 20);
    int off = (lvl == 0) ? 0  : (lvl == 1 ? 6400 : 8000);
    float sf = (float)(8 << lvl);
    int r = i - off;
    int iy = r / n, ix = r - iy * n;
    ax = (ix + 0.5f) * sf;
    ay = (iy + 0.5f) * sf;
}

// ---- Kernel 1: one BLOCK per (b,g). thr = 13th-largest align metric.
// Fast path: <13 positive metrics -> thr = 0. Also zeroes pam/pim/done
// (node boundary orders these inits before k_main). ----
__global__ __launch_bounds__(256) void k_thresh(
    const float* __restrict__ pd_scores, const float* __restrict__ pd_bboxes,
    const float* __restrict__ gt_bboxes, const float* __restrict__ mask_gt,
    float* __restrict__ thr, int* __restrict__ pam, int* __restrict__ pim,
    int* __restrict__ done,
    int B, int G, int NA)
{
    __shared__ float plist[PCAP];
    __shared__ int   pcnt;

    int w = blockIdx.x;
    int tid = threadIdx.x;
    if (tid == 0) {
        pam[w] = 0; pim[w] = 0; pcnt = 0;
        if ((w % G) == 0) done[w / G] = 0;    // barrier counter reset per replay
    }
    __syncthreads();

    if (mask_gt[w] == 0.f) { if (tid == 0) thr[w] = 0.f; return; }

    int b = w / G;
    float4 gb = *(const float4*)(gt_bboxes + (size_t)w * 4);
    const float* ps = pd_scores + (size_t)b * NA;
    const float* pb = pd_bboxes + (size_t)b * NA * 4;

    // analytic candidate rectangle per stride level (anchors form a grid)
    #pragma unroll
    for (int lvl = 0; lvl < 3; ++lvl) {
        const int n   = (lvl == 0) ? 80 : (lvl == 1 ? 40 : 20);
        const int off = (lvl == 0) ? 0  : (lvl == 1 ? 6400 : 8000);
        const float sf = (float)(8 << lvl);
        int ix0 = max(0,     (int)floorf(gb.x / sf - 0.5f));
        int iy0 = max(0,     (int)floorf(gb.y / sf - 0.5f));
        int ix1 = min(n - 1, (int)ceilf (gb.z / sf - 0.5f));
        int iy1 = min(n - 1, (int)ceilf (gb.w / sf - 0.5f));
        int wdt = ix1 - ix0 + 1, hgt = iy1 - iy0 + 1;
        if (wdt <= 0 || hgt <= 0) continue;
        int n_c = wdt * hgt;
        for (int c = tid; c < n_c; c += 256) {
            int ix = ix0 + (c % wdt);
            int iy = iy0 + (c / wdt);
            float ax = (ix + 0.5f) * sf;   // exact f32 == reference anc
            float ay = (iy + 0.5f) * sf;
            if (in_box(ax, ay, gb) != 0.f) {
                int a = off + iy * n + ix;
                float4 p = *(const float4*)(pb + (size_t)a * 4);
                float iou = iou_clip(gb, p);
                float sqs = sqrtf(fmaxf(ps[a], 0.f));
                float am = align_metric_f(sqs, iou, 1.f);
                if (am > 0.f) {
                    int idx = atomicAdd(&pcnt, 1);
                    if (idx < PCAP) plist[idx] = am;
                }
            }
        }
    }
    __syncthreads();

    int n = pcnt;
    if (n < TOPK_K) { if (tid == 0) thr[w] = 0.f; return; }

    // rare path: wave 0 computes top-13 of the positives list
    if (tid < 64) {
        int lane = tid;
        float t[KPAD];
        #pragma unroll
        for (int i = 0; i < KPAD; ++i) t[i] = 0.f;
        for (int j = lane; j < n; j += 64) {
            float v = plist[j];
            if (v > t[KPAD - 1]) {
                t[KPAD - 1] = v;
                #pragma unroll
                for (int i = KPAD - 1; i > 0; --i) {
                    float hi = fmaxf(t[i - 1], t[i]);
                    float lo = fminf(t[i - 1], t[i]);
                    t[i - 1] = hi; t[i] = lo;
                }
            }
        }
        for (int off = 1; off < 64; off <<= 1) {
            float o[KPAD], m[KPAD];
            #pragma unroll
            for (int i = 0; i < KPAD; ++i) o[i] = __shfl_xor(t[i], off, 64);
            #pragma unroll
            for (int i = 0; i < KPAD; ++i) m[i] = fmaxf(t[i], o[KPAD - 1 - i]);
            #pragma unroll
            for (int s = 8; s >= 1; s >>= 1) {
                #pragma unroll
                for (int i = 0; i < KPAD; ++i) {
                    if ((i & s) == 0) {
                        float hi = fmaxf(m[i], m[i + s]);
                        float lo = fminf(m[i], m[i + s]);
                        m[i] = hi; m[i + s] = lo;
                    }
                }
            }
            #pragma unroll
            for (int i = 0; i < KPAD; ++i) t[i] = m[i];
        }
        if (lane == 0) thr[w] = t[TOPK_K - 1];
    }
}

// ---- per-anchor resolve body (phase B). All lanes participate in wave ops;
// writes primary outputs + pam/pim; returns tgt/amv/isfg for phase C. ----
__device__ __forceinline__ void process_anchor(
    int idx, bool act, int lane,
    const float4* sbox, const float* smask, const float* sthr, const int* slab,
    const float* __restrict__ ps, const float* __restrict__ pb,
    size_t oNA, int bG,
    float* __restrict__ out_labels, float* __restrict__ out_bboxes,
    float* __restrict__ out_fg,
    int* __restrict__ pam, int* __restrict__ pim,
    int& tgt_r, float& amv_r, bool& fg_r)
{
    int NAm1_idx = idx;                    // idx already clamped by caller
    size_t o = oNA + NAm1_idx;
    float ax, ay; anc_xy(NAm1_idx, ax, ay);
    float4 p = *(const float4*)(pb + (size_t)NAm1_idx * 4);
    float sqs = sqrtf(fmaxf(ps[NAm1_idx], 0.f));

    // wave anchor-bbox reduce
    float mnx = ax, mxx = ax, mny = ay, mxy = ay;
    #pragma unroll
    for (int off = 32; off >= 1; off >>= 1) {
        mnx = fminf(mnx, __shfl_xor(mnx, off, 64));
        mxx = fmaxf(mxx, __shfl_xor(mxx, off, 64));
        mny = fminf(mny, __shfl_xor(mny, off, 64));
        mxy = fmaxf(mxy, __shfl_xor(mxy, off, 64));
    }

    // per-wave gt shortlist via ballot (ascending g preserved)
    float4 gl = sbox[lane];
    bool el = (smask[lane] != 0.f) &&
              (gl.x < mxx) && (gl.z > mnx) && (gl.y < mxy) && (gl.w > mny);
    unsigned long long sm = __ballot(el);

    int fg = 0, firstg = 0;
    unsigned long long mm = sm;
    while (mm) {
        int g = __ffsll((long long)mm) - 1;
        mm &= mm - 1;
        float4 gbb = sbox[g];
        if (act && in_box(ax, ay, gbb) != 0.f) {
            float iou = iou_clip(gbb, p);
            float am = align_metric_f(sqs, iou, 1.f);
            if (am >= sthr[g]) { if (fg == 0) firstg = g; ++fg; }
        }
    }

    int tgt = (fg == 1) ? firstg : 0;

    // wave-cooperative disputed resolution (lane g = gt g; all 64 gts)
    unsigned long long dm = __ballot(fg > 1);
    while (dm) {
        int l = __ffsll((long long)dm) - 1;
        dm &= dm - 1;
        float4 pl;
        pl.x = __shfl(p.x, l, 64); pl.y = __shfl(p.y, l, 64);
        pl.z = __shfl(p.z, l, 64); pl.w = __shfl(p.w, l, 64);
        float iou = iou_clip(gl, pl);
        int g = lane;
        #pragma unroll
        for (int off = 32; off >= 1; off >>= 1) {
            float oi = __shfl_xor(iou, off, 64);
            int   og = __shfl_xor(g,   off, 64);
            if (oi > iou || (oi == iou && og < g)) { iou = oi; g = og; }
        }
        if (lane == l) tgt = g;   // first-occurrence argmax == jnp.argmax
    }

    tgt_r = tgt;
    bool isfg = (fg != 0);
    fg_r = isfg;
    amv_r = 0.f;
    if (!act) return;

    // epilogue: recompute am/iou at target (bit-identical helper path)
    float4 gbt = sbox[tgt];
    float vt  = in_box(ax, ay, gbt) * smask[tgt];
    float iout = iou_clip(gbt, p);
    float amt = align_metric_f(sqs, iout, vt);
    float amv = isfg ? amt : 0.f;    // am * mask_pos (valid included)
    float iov = isfg ? iout : 0.f;   // overlaps * mask_pos (no valid mult)
    amv_r = amv;

    out_labels[o] = (float)slab[tgt];
    *(float4*)(out_bboxes + o * 4) = gbt;
    out_fg[o] = isfg ? 1.f : 0.f;

    if (isfg) {
        atomicMax(&pam[bG + tgt], __float_as_int(amv));  // vals>=0: int order == float order
        atomicMax(&pim[bG + tgt], __float_as_int(iov));
    }
}

// ---- Kernel 2: 256 blocks x 1024 threads (1 block/CU -> all co-resident).
// 8 blocks per batch. Phase B: resolve+outputs+pam/pim. Per-batch barrier
// (arrive counter zeroed by k_thresh via the node boundary). Phase C: scores
// from register-held tgt/amv + LDS-staged pam/pim. ----
__global__ __launch_bounds__(1024) void k_main(
    const float* __restrict__ pd_scores, const float* __restrict__ pd_bboxes,
    const int* __restrict__ gt_labels,
    const float* __restrict__ gt_bboxes, const float* __restrict__ mask_gt,
    const float* __restrict__ thr,
    float* __restrict__ out_labels, float* __restrict__ out_bboxes,
    float* __restrict__ out_scores, float* __restrict__ out_fg,
    int* __restrict__ pam, int* __restrict__ pim, int* __restrict__ done,
    int B, int G, int NA)
{
    __shared__ float4 sbox[64];
    __shared__ float  smask[64];
    __shared__ float  sthr[64];
    __shared__ int    slab[64];
    __shared__ int    spam[64];
    __shared__ int    spim[64];

    const int b   = blockIdx.x >> 3;
    const int s   = blockIdx.x & 7;
    const int tid = threadIdx.x;
    const int lane = tid & 63;
    const int bG  = b * G;
    const int SL  = (NA + 7) / 8;            // 1050
    const int base = s * SL;
    const size_t oNA = (size_t)b * NA;

    if (tid < 64) {
        sbox[tid]  = *(const float4*)(gt_bboxes + ((size_t)bG + tid) * 4);
        smask[tid] = mask_gt[bG + tid];
        sthr[tid]  = thr[bG + tid];
        int l = gt_labels[bG + tid];
        slab[tid]  = (l < 0) ? 0 : l;
    }
    __syncthreads();

    const float* ps = pd_scores + oNA;
    const float* pb = pd_bboxes + oNA * 4;

    // ---- phase B: two statically-named iterations (1050 <= 2*1024) ----
    int loc0 = tid;            bool act0 = (loc0 < SL) && (base + loc0 < NA);
    int loc1 = 1024 + tid;     bool act1 = (loc1 < SL) && (base + loc1 < NA);
    int idx0 = act0 ? (base + loc0) : (NA - 1);
    int idx1 = act1 ? (base + loc1) : (NA - 1);

    int tgt0, tgt1; float amv0, amv1; bool fgb0, fgb1;
    process_anchor(idx0, act0, lane, sbox, smask, sthr, slab, ps, pb, oNA, bG,
                   out_labels, out_bboxes, out_fg, pam, pim, tgt0, amv0, fgb0);
    process_anchor(idx1, act1, lane, sbox, smask, sthr, slab, ps, pb, oNA, bG,
                   out_labels, out_bboxes, out_fg, pam, pim, tgt1, amv1, fgb1);

    // ---- per-batch barrier: 8 blocks arrive, spin on done[b] ----
    __threadfence();
    __syncthreads();
    if (tid == 0) {
        __hip_atomic_fetch_add(&done[b], 1, __ATOMIC_ACQ_REL, __HIP_MEMORY_SCOPE_AGENT);
        while (__hip_atomic_load(&done[b], __ATOMIC_ACQUIRE, __HIP_MEMORY_SCOPE_AGENT) < 8)
            __builtin_amdgcn_s_sleep(8);
    }
    __syncthreads();
    __threadfence();

    if (tid < 64) { spam[tid] = pam[bG + tid]; spim[tid] = pim[bG + tid]; }
    __syncthreads();

    // ---- phase C: normalized target scores (state held in registers) ----
    if (act0) {
        float pa = __int_as_float(spam[tgt0]);
        float pi = __int_as_float(spim[tgt0]);
        float wgt = amv0 / (pa + 1e-9f) * pi;
        out_scores[oNA + idx0] = ((slab[tgt0] == 0) ? 1.f : 0.f) * wgt;
    }
    if (act1) {
        float pa = __int_as_float(spam[tgt1]);
        float pi = __int_as_float(spim[tgt1]);
        float wgt = amv1 / (pa + 1e-9f) * pi;
        out_scores[oNA + idx1] = ((slab[tgt1] == 0) ? 1.f : 0.f) * wgt;
    }
}

extern "C" void kernel_launch(void* const* d_in, const int* in_sizes, int n_in,
                              void* d_out, int out_size, void* d_ws, size_t ws_size,
                              hipStream_t stream) {
    const float* pd_scores = (const float*)d_in[0];
    const float* pd_bboxes = (const float*)d_in[1];
    const int*   gt_labels = (const int*)d_in[3];
    const float* gt_bboxes = (const float*)d_in[4];
    const float* mask_gt   = (const float*)d_in[5];

    int NA = in_sizes[2] / 2;
    int B  = in_sizes[0] / NA;
    int G  = in_sizes[4] / (B * 4);

    float* out = (float*)d_out;
    float* out_labels = out;                               // (B,NA)
    float* out_bboxes = out_labels + (size_t)B * NA;       // (B,NA,4)
    float* out_scores = out_bboxes + (size_t)B * NA * 4;   // (B,NA,1)
    float* out_fg     = out_scores + (size_t)B * NA;       // (B,NA)

    int BG = B * G;
    float* thr  = (float*)d_ws;               // BG
    int*   pam  = (int*)(thr + BG);           // BG
    int*   pim  = pam + BG;                   // BG
    int*   done = pim + BG;                   // B

    k_thresh<<<dim3(BG), dim3(256), 0, stream>>>(
        pd_scores, pd_bboxes, gt_bboxes, mask_gt, thr, pam, pim, done, B, G, NA);

    k_main<<<dim3(B * 8), dim3(1024), 0, stream>>>(
        pd_scores, pd_bboxes, gt_labels, gt_bboxes, mask_gt, thr,
        out_labels, out_bboxes, out_scores, out_fg, pam, pim, done, B, G, NA);
}

// Round 13
// 169.649 us; speedup vs baseline: 1.0493x; 1.0493x over previous
//
#include <hip/hip_runtime.h>

#define TOPK_K 13
#define KPAD 16
#define PCAP 384   // > max in-box anchors per gt (<=336 for 128px box)

// ---- shared math helpers: every am/IoU value in all kernels flows through
// these, so threshold comparisons and argmax are bit-exact vs each other. ----

__device__ __forceinline__ float iou_clip(const float4 g, const float4 p) {
    float ix1 = fmaxf(g.x, p.x), iy1 = fmaxf(g.y, p.y);
    float ix2 = fminf(g.z, p.z), iy2 = fminf(g.w, p.w);
    float iw = fmaxf(ix2 - ix1, 0.f);
    float ih = fmaxf(iy2 - iy1, 0.f);
    float inter = iw * ih;
    float a1 = (g.z - g.x) * (g.w - g.y);
    float a2 = (p.z - p.x) * (p.w - p.y);
    float iou = inter / (a1 + a2 - inter + 1e-7f);
    return fmaxf(iou, 0.f);
}

__device__ __forceinline__ float in_box(float ax, float ay, const float4 g) {
    float m = fminf(fminf(ax - g.x, ay - g.y), fminf(g.z - ax, g.w - ay));
    return (m > 0.f) ? 1.f : 0.f;
}

__device__ __forceinline__ float align_metric_f(float sqs, float iou, float valid) {
    float p2 = iou * iou;
    float p6 = p2 * p2 * p2;
    return sqs * p6 * valid;
}

// anchor index -> center coords (bit-exact vs reference (arange+0.5)*s)
__device__ __forceinline__ void anc_xy(int i, float& ax, float& ay) {
    int lvl = (i < 6400) ? 0 : (i < 8000 ? 1 : 2);
    int n   = (lvl == 0) ? 80 : (lvl == 1 ? 40 : 20);
    int off = (lvl == 0) ? 0  : (lvl == 1 ? 6400 : 8000);
    float sf = (float)(8 << lvl);
    int r = i - off;
    int iy = r / n, ix = r - iy * n;
    ax = (ix + 0.5f) * sf;
    ay = (iy + 0.5f) * sf;
}

// ---- Node 1: block = 256 contiguous anchors of batch b. Computes exact
// thresholds for the block's gt-shortlist (block-cooperative, full rectangle),
// resolves its anchors (wave-coop disputes), writes primary outputs +
// per-block pam/pim partial maxima (plain stores -> no init, no atomics). ----
__global__ __launch_bounds__(256) void k_main(
    const float* __restrict__ pd_scores, const float* __restrict__ pd_bboxes,
    const int* __restrict__ gt_labels,
    const float* __restrict__ gt_bboxes, const float* __restrict__ mask_gt,
    float* __restrict__ out_labels, float* __restrict__ out_bboxes,
    float* __restrict__ out_fg,
    int* __restrict__ ws_tgt, float* __restrict__ ws_amv,
    int* __restrict__ pam_part, int* __restrict__ pim_part,
    int B, int G, int NA, int NBX)
{
    __shared__ float4 sbox[64];
    __shared__ float  smask[64];
    __shared__ float  sthr[64];
    __shared__ int    slab[64];
    __shared__ int    spam[64];
    __shared__ int    spim[64];
    __shared__ float  sred[4][4];
    __shared__ int    slist[64];
    __shared__ int    scount;
    __shared__ float  plist[PCAP];
    __shared__ int    pcnt;

    const int b   = blockIdx.y;
    const int tid = threadIdx.x;
    const int lane = tid & 63;
    const int wv   = tid >> 6;
    const int bG   = b * G;

    if (tid < 64) {
        sbox[tid]  = *(const float4*)(gt_bboxes + ((size_t)bG + tid) * 4);
        smask[tid] = mask_gt[bG + tid];
        int l = gt_labels[bG + tid];
        slab[tid]  = (l < 0) ? 0 : l;
        spam[tid]  = 0;
        spim[tid]  = 0;
    }

    int a = blockIdx.x * 256 + tid;
    bool act = (a < NA);                 // no early return: lanes serve wave ops
    int ac = act ? a : (NA - 1);
    size_t o = (size_t)b * NA + ac;
    float ax, ay; anc_xy(ac, ax, ay);

    // block anchor-bbox reduce (wave shfl + LDS combine)
    float mnx = ax, mxx = ax, mny = ay, mxy = ay;
    #pragma unroll
    for (int off = 32; off >= 1; off >>= 1) {
        mnx = fminf(mnx, __shfl_xor(mnx, off, 64));
        mxx = fmaxf(mxx, __shfl_xor(mxx, off, 64));
        mny = fminf(mny, __shfl_xor(mny, off, 64));
        mxy = fmaxf(mxy, __shfl_xor(mxy, off, 64));
    }
    if (lane == 0) { sred[wv][0] = mnx; sred[wv][1] = mxx; sred[wv][2] = mny; sred[wv][3] = mxy; }
    __syncthreads();
    float bmnx = fminf(fminf(sred[0][0], sred[1][0]), fminf(sred[2][0], sred[3][0]));
    float bmxx = fmaxf(fmaxf(sred[0][1], sred[1][1]), fmaxf(sred[2][1], sred[3][1]));
    float bmny = fminf(fminf(sred[0][2], sred[1][2]), fmaxf(sred[2][2], sred[3][2]));
    float bmxy = fmaxf(fmaxf(sred[0][3], sred[1][3]), fmaxf(sred[2][3], sred[3][3]));
    // note: bmny uses fminf on the last pair too
    bmny = fminf(fminf(sred[0][2], sred[1][2]), fminf(sred[2][2], sred[3][2]));

    // shortlist: gts whose box could strictly contain an anchor in the bbox
    if (tid < 64) {
        float4 gbb = sbox[tid];
        bool el = (smask[tid] != 0.f) &&
                  (gbb.x < bmxx) && (gbb.z > bmnx) &&
                  (gbb.y < bmxy) && (gbb.w > bmny);
        unsigned long long bal = __ballot(el);
        if (el) slist[(int)__popcll(bal & ((1ull << tid) - 1ull))] = tid;
        if (tid == 0) scount = (int)__popcll(bal);
    }
    __syncthreads();
    const int nsl = scount;

    const float* ps = pd_scores + (size_t)b * NA;
    const float* pb = pd_bboxes + (size_t)b * NA * 4;

    // ---- thresholds for shortlisted gts (exact: full analytic rectangle) ----
    for (int j = 0; j < nsl; ++j) {
        int g = slist[j];
        if (tid == 0) pcnt = 0;
        __syncthreads();
        float4 gb = sbox[g];
        #pragma unroll
        for (int lvl = 0; lvl < 3; ++lvl) {
            const int n   = (lvl == 0) ? 80 : (lvl == 1 ? 40 : 20);
            const int off = (lvl == 0) ? 0  : (lvl == 1 ? 6400 : 8000);
            const float sf = (float)(8 << lvl);
            int ix0 = max(0,     (int)floorf(gb.x / sf - 0.5f));
            int iy0 = max(0,     (int)floorf(gb.y / sf - 0.5f));
            int ix1 = min(n - 1, (int)ceilf (gb.z / sf - 0.5f));
            int iy1 = min(n - 1, (int)ceilf (gb.w / sf - 0.5f));
            int wdt = ix1 - ix0 + 1, hgt = iy1 - iy0 + 1;
            if (wdt <= 0 || hgt <= 0) continue;
            int n_c = wdt * hgt;
            for (int c = tid; c < n_c; c += 256) {
                int ix = ix0 + (c % wdt);
                int iy = iy0 + (c / wdt);
                float axx = (ix + 0.5f) * sf;   // exact f32 == reference anc
                float ayy = (iy + 0.5f) * sf;
                if (in_box(axx, ayy, gb) != 0.f) {
                    int aa = off + iy * n + ix;
                    float4 p = *(const float4*)(pb + (size_t)aa * 4);
                    float iou = iou_clip(gb, p);
                    float sqs = sqrtf(fmaxf(ps[aa], 0.f));
                    float am = align_metric_f(sqs, iou, 1.f);
                    if (am > 0.f) {
                        int idx = atomicAdd(&pcnt, 1);
                        if (idx < PCAP) plist[idx] = am;
                    }
                }
            }
        }
        __syncthreads();
        int n = pcnt;
        if (n < TOPK_K) {
            if (tid == 0) sthr[g] = 0.f;   // padded zeros dominate the top-13
        } else if (tid < 64) {
            // rare path: wave 0 computes top-13 of the positives list
            float t[KPAD];
            #pragma unroll
            for (int i = 0; i < KPAD; ++i) t[i] = 0.f;
            for (int jj = lane; jj < n; jj += 64) {
                float v = plist[jj];
                if (v > t[KPAD - 1]) {
                    t[KPAD - 1] = v;
                    #pragma unroll
                    for (int i = KPAD - 1; i > 0; --i) {
                        float hi = fmaxf(t[i - 1], t[i]);
                        float lo = fminf(t[i - 1], t[i]);
                        t[i - 1] = hi; t[i] = lo;
                    }
                }
            }
            for (int off = 1; off < 64; off <<= 1) {
                float ot[KPAD], m[KPAD];
                #pragma unroll
                for (int i = 0; i < KPAD; ++i) ot[i] = __shfl_xor(t[i], off, 64);
                #pragma unroll
                for (int i = 0; i < KPAD; ++i) m[i] = fmaxf(t[i], ot[KPAD - 1 - i]);
                #pragma unroll
                for (int s = 8; s >= 1; s >>= 1) {
                    #pragma unroll
                    for (int i = 0; i < KPAD; ++i) {
                        if ((i & s) == 0) {
                            float hi = fmaxf(m[i], m[i + s]);
                            float lo = fminf(m[i], m[i + s]);
                            m[i] = hi; m[i + s] = lo;
                        }
                    }
                }
                #pragma unroll
                for (int i = 0; i < KPAD; ++i) t[i] = m[i];
            }
            if (tid == 0) sthr[g] = t[TOPK_K - 1];
        }
        __syncthreads();   // before plist/pcnt reuse and sthr read
    }

    // ---- per-anchor resolve ----
    float4 p = *(const float4*)(pb + (size_t)ac * 4);
    float sqs = sqrtf(fmaxf(ps[ac], 0.f));

    int fg = 0, firstg = 0;
    for (int j = 0; j < nsl; ++j) {
        int g = slist[j];                       // ascending g (ballot order)
        float4 gbb = sbox[g];
        if (act && in_box(ax, ay, gbb) != 0.f) {
            float iou = iou_clip(gbb, p);
            float am = align_metric_f(sqs, iou, 1.f);
            if (am >= sthr[g]) { if (fg == 0) firstg = g; ++fg; }
        }
    }

    int tgt = (fg == 1) ? firstg : 0;

    // wave-cooperative disputed resolution (lane g = gt g; all 64 gts)
    float4 gl = sbox[lane];
    unsigned long long dm = __ballot(fg > 1);
    while (dm) {
        int l = __ffsll((long long)dm) - 1;
        dm &= dm - 1;
        float4 pl;
        pl.x = __shfl(p.x, l, 64); pl.y = __shfl(p.y, l, 64);
        pl.z = __shfl(p.z, l, 64); pl.w = __shfl(p.w, l, 64);
        float iou = iou_clip(gl, pl);
        int g = lane;
        #pragma unroll
        for (int off = 32; off >= 1; off >>= 1) {
            float oi = __shfl_xor(iou, off, 64);
            int   og = __shfl_xor(g,   off, 64);
            if (oi > iou || (oi == iou && og < g)) { iou = oi; g = og; }
        }
        if (lane == l) tgt = g;   // first-occurrence argmax == jnp.argmax
    }

    if (act) {
        // epilogue: recompute am/iou at target (bit-identical helper path)
        float4 gbt = sbox[tgt];
        float vt  = in_box(ax, ay, gbt) * smask[tgt];
        float iout = iou_clip(gbt, p);
        float amt = align_metric_f(sqs, iout, vt);
        bool isfg = (fg != 0);
        float amv = isfg ? amt : 0.f;    // am * mask_pos (valid included)
        float iov = isfg ? iout : 0.f;   // overlaps * mask_pos (no valid mult)

        out_labels[o] = (float)slab[tgt];
        *(float4*)(out_bboxes + o * 4) = gbt;
        out_fg[o] = isfg ? 1.f : 0.f;
        ws_tgt[o] = tgt;
        ws_amv[o] = amv;

        if (isfg) {
            atomicMax(&spam[tgt], __float_as_int(amv));  // LDS; vals>=0
            atomicMax(&spim[tgt], __float_as_int(iov));
        }
    }
    __syncthreads();

    // per-block pam/pim partial slice (plain stores -> no init dependency)
    if (tid < 64) {
        size_t pb_off = ((size_t)b * NBX + blockIdx.x) * 64 + tid;
        pam_part[pb_off] = spam[tid];
        pim_part[pb_off] = spim[tid];
    }
}

// ---- Node 2: reduce pam/pim partials (33 per (b,g)) in LDS, then compute
// normalized target scores per anchor. ----
__global__ __launch_bounds__(256) void k_scores(
    const int* __restrict__ ws_tgt, const float* __restrict__ ws_amv,
    const int* __restrict__ pam_part, const int* __restrict__ pim_part,
    const float* __restrict__ out_labels,
    float* __restrict__ out_scores,
    int B, int G, int NA, int NBX)
{
    __shared__ int spam[64];
    __shared__ int spim[64];

    int b = blockIdx.y;
    int tid = threadIdx.x;
    if (tid < 64) {
        int mpa = 0, mpi = 0;
        for (int j = 0; j < NBX; ++j) {
            size_t off = ((size_t)b * NBX + j) * 64 + tid;
            mpa = max(mpa, pam_part[off]);
            mpi = max(mpi, pim_part[off]);
        }
        spam[tid] = mpa;
        spim[tid] = mpi;
    }
    __syncthreads();

    int a = blockIdx.x * blockDim.x + tid;
    if (a >= NA) return;
    size_t o = (size_t)b * NA + a;

    int tgt = ws_tgt[o];
    float amv = ws_amv[o];
    float pa = __int_as_float(spam[tgt]);
    float pi = __int_as_float(spim[tgt]);
    float wgt = amv / (pa + 1e-9f) * pi;
    float onehot = (out_labels[o] == 0.f) ? 1.f : 0.f;   // NC==1
    out_scores[o] = onehot * wgt;
}

extern "C" void kernel_launch(void* const* d_in, const int* in_sizes, int n_in,
                              void* d_out, int out_size, void* d_ws, size_t ws_size,
                              hipStream_t stream) {
    const float* pd_scores = (const float*)d_in[0];
    const float* pd_bboxes = (const float*)d_in[1];
    const int*   gt_labels = (const int*)d_in[3];
    const float* gt_bboxes = (const float*)d_in[4];
    const float* mask_gt   = (const float*)d_in[5];

    int NA = in_sizes[2] / 2;
    int B  = in_sizes[0] / NA;
    int G  = in_sizes[4] / (B * 4);
    int NBX = (NA + 255) / 256;               // 33

    float* out = (float*)d_out;
    float* out_labels = out;                               // (B,NA)
    float* out_bboxes = out_labels + (size_t)B * NA;       // (B,NA,4)
    float* out_scores = out_bboxes + (size_t)B * NA * 4;   // (B,NA,1)
    float* out_fg     = out_scores + (size_t)B * NA;       // (B,NA)

    size_t BNA = (size_t)B * NA;
    int*   ws_tgt   = (int*)d_ws;                       // BNA
    float* ws_amv   = (float*)(ws_tgt + BNA);           // BNA
    int*   pam_part = (int*)(ws_amv + BNA);             // B*NBX*64
    int*   pim_part = pam_part + (size_t)B * NBX * 64;  // B*NBX*64

    k_main<<<dim3(NBX, B), dim3(256), 0, stream>>>(
        pd_scores, pd_bboxes, gt_labels, gt_bboxes, mask_gt,
        out_labels, out_bboxes, out_fg, ws_tgt, ws_amv,
        pam_part, pim_part, B, G, NA, NBX);

    k_scores<<<dim3(NBX, B), dim3(256), 0, stream>>>(
        ws_tgt, ws_amv, pam_part, pim_part, out_labels, out_scores,
        B, G, NA, NBX);
}

// Round 14
// 39.540 us; speedup vs baseline: 4.5022x; 4.2905x over previous
//
#include <hip/hip_runtime.h>

#define TOPK_K 13
#define KPAD 16
#define PCAP 384   // > max in-box anchors per gt (<=336 for 128px box)

// ---- shared math helpers: every am/IoU value in all kernels flows through
// these, so threshold comparisons and argmax are bit-exact vs each other. ----

__device__ __forceinline__ float iou_clip(const float4 g, const float4 p) {
    float ix1 = fmaxf(g.x, p.x), iy1 = fmaxf(g.y, p.y);
    float ix2 = fminf(g.z, p.z), iy2 = fminf(g.w, p.w);
    float iw = fmaxf(ix2 - ix1, 0.f);
    float ih = fmaxf(iy2 - iy1, 0.f);
    float inter = iw * ih;
    float a1 = (g.z - g.x) * (g.w - g.y);
    float a2 = (p.z - p.x) * (p.w - p.y);
    float iou = inter / (a1 + a2 - inter + 1e-7f);
    return fmaxf(iou, 0.f);
}

__device__ __forceinline__ float in_box(float ax, float ay, const float4 g) {
    float m = fminf(fminf(ax - g.x, ay - g.y), fminf(g.z - ax, g.w - ay));
    return (m > 0.f) ? 1.f : 0.f;
}

__device__ __forceinline__ float align_metric_f(float sqs, float iou, float valid) {
    float p2 = iou * iou;
    float p6 = p2 * p2 * p2;
    return sqs * p6 * valid;
}

// anchor index -> center coords (bit-exact vs reference (arange+0.5)*s)
__device__ __forceinline__ void anc_xy(int i, float& ax, float& ay) {
    int lvl = (i < 6400) ? 0 : (i < 8000 ? 1 : 2);
    int n   = (lvl == 0) ? 80 : (lvl == 1 ? 40 : 20);
    int off = (lvl == 0) ? 0  : (lvl == 1 ? 6400 : 8000);
    float sf = (float)(8 << lvl);
    int r = i - off;
    int iy = r / n, ix = r - iy * n;
    ax = (ix + 0.5f) * sf;
    ay = (iy + 0.5f) * sf;
}

// ---- Kernel 1: one BLOCK (256 thr) per (b,g). thr = 13th-largest align
// metric. Fast path: <13 positive metrics -> thr = 0 (reference row is padded
// with zeros). Rare path: wave 0 sorts the compact positives list. Also
// zeroes pam/pim. ---- (r11-verbatim, proven)
__global__ __launch_bounds__(256) void k_thresh(
    const float* __restrict__ pd_scores, const float* __restrict__ pd_bboxes,
    const float* __restrict__ gt_bboxes, const float* __restrict__ mask_gt,
    float* __restrict__ thr, int* __restrict__ pam, int* __restrict__ pim,
    int B, int G, int NA)
{
    __shared__ float plist[PCAP];
    __shared__ int   pcnt;

    int w = blockIdx.x;
    int tid = threadIdx.x;
    if (tid == 0) { pam[w] = 0; pim[w] = 0; pcnt = 0; }
    __syncthreads();

    if (mask_gt[w] == 0.f) { if (tid == 0) thr[w] = 0.f; return; }

    int b = w / G;
    float4 gb = *(const float4*)(gt_bboxes + (size_t)w * 4);
    const float* ps = pd_scores + (size_t)b * NA;
    const float* pb = pd_bboxes + (size_t)b * NA * 4;

    // analytic candidate rectangle per stride level (anchors form a grid)
    #pragma unroll
    for (int lvl = 0; lvl < 3; ++lvl) {
        const int n   = (lvl == 0) ? 80 : (lvl == 1 ? 40 : 20);
        const int off = (lvl == 0) ? 0  : (lvl == 1 ? 6400 : 8000);
        const float sf = (float)(8 << lvl);
        int ix0 = max(0,     (int)floorf(gb.x / sf - 0.5f));
        int iy0 = max(0,     (int)floorf(gb.y / sf - 0.5f));
        int ix1 = min(n - 1, (int)ceilf (gb.z / sf - 0.5f));
        int iy1 = min(n - 1, (int)ceilf (gb.w / sf - 0.5f));
        int wdt = ix1 - ix0 + 1, hgt = iy1 - iy0 + 1;
        if (wdt <= 0 || hgt <= 0) continue;
        int n_c = wdt * hgt;
        for (int c = tid; c < n_c; c += 256) {
            int ix = ix0 + (c % wdt);
            int iy = iy0 + (c / wdt);
            float ax = (ix + 0.5f) * sf;   // exact f32 == reference anc
            float ay = (iy + 0.5f) * sf;
            if (in_box(ax, ay, gb) != 0.f) {
                int a = off + iy * n + ix;
                float4 p = *(const float4*)(pb + (size_t)a * 4);
                float iou = iou_clip(gb, p);
                float sqs = sqrtf(fmaxf(ps[a], 0.f));
                float am = align_metric_f(sqs, iou, 1.f);
                if (am > 0.f) {
                    int idx = atomicAdd(&pcnt, 1);
                    if (idx < PCAP) plist[idx] = am;
                }
            }
        }
    }
    __syncthreads();

    int n = pcnt;
    if (n < TOPK_K) { if (tid == 0) thr[w] = 0.f; return; }

    // rare path: wave 0 computes top-13 of the positives list
    if (tid < 64) {
        int lane = tid;
        float t[KPAD];
        #pragma unroll
        for (int i = 0; i < KPAD; ++i) t[i] = 0.f;
        for (int j = lane; j < n; j += 64) {
            float v = plist[j];
            if (v > t[KPAD - 1]) {
                t[KPAD - 1] = v;
                #pragma unroll
                for (int i = KPAD - 1; i > 0; --i) {
                    float hi = fmaxf(t[i - 1], t[i]);
                    float lo = fminf(t[i - 1], t[i]);
                    t[i - 1] = hi; t[i] = lo;
                }
            }
        }
        for (int off = 1; off < 64; off <<= 1) {
            float o[KPAD], m[KPAD];
            #pragma unroll
            for (int i = 0; i < KPAD; ++i) o[i] = __shfl_xor(t[i], off, 64);
            #pragma unroll
            for (int i = 0; i < KPAD; ++i) m[i] = fmaxf(t[i], o[KPAD - 1 - i]);
            #pragma unroll
            for (int s = 8; s >= 1; s >>= 1) {
                #pragma unroll
                for (int i = 0; i < KPAD; ++i) {
                    if ((i & s) == 0) {
                        float hi = fmaxf(m[i], m[i + s]);
                        float lo = fminf(m[i], m[i + s]);
                        m[i] = hi; m[i + s] = lo;
                    }
                }
            }
            #pragma unroll
            for (int i = 0; i < KPAD; ++i) t[i] = m[i];
        }
        if (lane == 0) thr[w] = t[TOPK_K - 1];
    }
}

// ---- Kernel 2: per-(b,anchor). Per-wave gt shortlist; disputes resolved by
// BLOCK-BATCHED per-thread argmax (LDS compaction, ILP-rich 64-gt loop; no
// dependent cross-lane chains). First-occurrence argmax == jnp.argmax. ----
__global__ __launch_bounds__(256) void k_assign(
    const float* __restrict__ pd_scores, const float* __restrict__ pd_bboxes,
    const int* __restrict__ gt_labels,
    const float* __restrict__ gt_bboxes, const float* __restrict__ mask_gt,
    const float* __restrict__ thr,
    float* __restrict__ out_labels, float* __restrict__ out_bboxes,
    float* __restrict__ out_fg,
    int* __restrict__ ws_tgt, float* __restrict__ ws_amv,
    int* __restrict__ pam, int* __restrict__ pim,
    int B, int G, int NA)
{
    __shared__ float4 sbox[64];
    __shared__ float  smask[64];
    __shared__ float  sthr[64];
    __shared__ int    slab[64];
    __shared__ float  sred[4][4];     // per-wave {minx,maxx,miny,maxy}
    __shared__ int    slist[64];
    __shared__ int    scount;
    __shared__ float4 dbox[256];      // disputed pred boxes
    __shared__ int    dtgt[256];      // resolved targets
    __shared__ int    dcnt;

    int b = blockIdx.y;
    int tid = threadIdx.x;
    if (tid == 0) dcnt = 0;
    if (tid < 64) {
        sbox[tid]  = *(const float4*)(gt_bboxes + ((size_t)b * G + tid) * 4);
        smask[tid] = mask_gt[b * G + tid];
        sthr[tid]  = thr[b * G + tid];
        int l = gt_labels[b * G + tid];
        slab[tid]  = (l < 0) ? 0 : l;
    }

    int a = blockIdx.x * blockDim.x + tid;
    bool act = (a < NA);                 // no early return until after last sync
    int lane = tid & 63;
    int wv = tid >> 6;
    int ac = act ? a : (NA - 1);
    size_t o = (size_t)b * NA + ac;

    float ax, ay; anc_xy(ac, ax, ay);

    // block anchor-bbox reduce (wave shfl + LDS combine)
    float mnx = ax, mxx = ax, mny = ay, mxy = ay;
    #pragma unroll
    for (int off = 32; off >= 1; off >>= 1) {
        mnx = fminf(mnx, __shfl_xor(mnx, off, 64));
        mxx = fmaxf(mxx, __shfl_xor(mxx, off, 64));
        mny = fminf(mny, __shfl_xor(mny, off, 64));
        mxy = fmaxf(mxy, __shfl_xor(mxy, off, 64));
    }
    if (lane == 0) { sred[wv][0] = mnx; sred[wv][1] = mxx; sred[wv][2] = mny; sred[wv][3] = mxy; }
    __syncthreads();
    float bmnx = fminf(fminf(sred[0][0], sred[1][0]), fminf(sred[2][0], sred[3][0]));
    float bmxx = fmaxf(fmaxf(sred[0][1], sred[1][1]), fmaxf(sred[2][1], sred[3][1]));
    float bmny = fminf(fminf(sred[0][2], sred[1][2]), fminf(sred[2][2], sred[3][2]));
    float bmxy = fmaxf(fmaxf(sred[0][3], sred[1][3]), fmaxf(sred[2][3], sred[3][3]));

    // shortlist: gts whose box can strictly contain some anchor in the bbox
    if (tid < 64) {
        float4 gbb = sbox[tid];
        bool el = (smask[tid] != 0.f) &&
                  (gbb.x < bmxx) && (gbb.z > bmnx) &&
                  (gbb.y < bmxy) && (gbb.w > bmny);
        unsigned long long bal = __ballot(el);
        if (el) slist[(int)__popcll(bal & ((1ull << tid) - 1ull))] = tid;
        if (tid == 0) scount = (int)__popcll(bal);
    }
    __syncthreads();
    int nsl = scount;

    float4 p = *(const float4*)(pd_bboxes + o * 4);
    float sqs = sqrtf(fmaxf(pd_scores[o], 0.f));

    int fg = 0, firstg = 0;
    for (int j = 0; j < nsl; ++j) {
        int g = slist[j];                       // ascending g (ballot order)
        float4 gbb = sbox[g];
        if (act && in_box(ax, ay, gbb) != 0.f) {
            float iou = iou_clip(gbb, p);
            float am = align_metric_f(sqs, iou, 1.f);
            if (am >= sthr[g]) { if (fg == 0) firstg = g; ++fg; }
        }
    }

    int tgt = (fg == 1) ? firstg : 0;

    // ---- batched dispute resolution: compact -> per-thread 64-gt argmax ----
    bool disp = (fg > 1);
    int slot = -1;
    if (disp) { slot = atomicAdd(&dcnt, 1); dbox[slot] = p; }
    __syncthreads();
    int nd = dcnt;
    if (tid < nd) {
        float4 pp = dbox[tid];
        float bi = -1.f; int bg = 0;
        #pragma unroll 4
        for (int g = 0; g < 64; ++g) {
            float iou = iou_clip(sbox[g], pp);
            if (iou > bi) { bi = iou; bg = g; }   // strict > = first occurrence
        }
        dtgt[tid] = bg;
    }
    __syncthreads();
    if (disp) tgt = dtgt[slot];

    if (!act) return;

    // epilogue: recompute am/iou at target (bit-identical helper path)
    float4 gbt = sbox[tgt];
    float vt  = in_box(ax, ay, gbt) * smask[tgt];
    float iout = iou_clip(gbt, p);
    float amt = align_metric_f(sqs, iout, vt);
    bool isfg = (fg != 0);
    float amv = isfg ? amt : 0.f;    // am * mask_pos (valid included)
    float iov = isfg ? iout : 0.f;   // overlaps * mask_pos (no valid mult)

    out_labels[o] = (float)slab[tgt];
    *(float4*)(out_bboxes + o * 4) = gbt;
    out_fg[o] = isfg ? 1.f : 0.f;
    ws_tgt[o] = tgt;
    ws_amv[o] = amv;

    if (isfg) {
        int gi = b * G + tgt;
        atomicMax(&pam[gi], __float_as_int(amv));  // vals>=0: int order == float order
        atomicMax(&pim[gi], __float_as_int(iov));
    }
}

// ---- Kernel 3: normalized target scores (pam/pim staged per-block). ----
__global__ __launch_bounds__(256) void k_scores(
    const int* __restrict__ ws_tgt, const float* __restrict__ ws_amv,
    const int* __restrict__ pam, const int* __restrict__ pim,
    const float* __restrict__ out_labels,
    float* __restrict__ out_scores,
    int B, int G, int NA)
{
    __shared__ int spam[64];
    __shared__ int spim[64];

    int b = blockIdx.y;
    int tid = threadIdx.x;
    if (tid < 64) {
        spam[tid] = pam[b * G + tid];
        spim[tid] = pim[b * G + tid];
    }
    __syncthreads();

    int a = blockIdx.x * blockDim.x + tid;
    if (a >= NA) return;
    size_t o = (size_t)b * NA + a;

    int tgt = ws_tgt[o];
    float amv = ws_amv[o];
    float pa = __int_as_float(spam[tgt]);
    float pi = __int_as_float(spim[tgt]);
    float wgt = amv / (pa + 1e-9f) * pi;
    float onehot = (out_labels[o] == 0.f) ? 1.f : 0.f;   // NC==1
    out_scores[o] = onehot * wgt;
}

extern "C" void kernel_launch(void* const* d_in, const int* in_sizes, int n_in,
                              void* d_out, int out_size, void* d_ws, size_t ws_size,
                              hipStream_t stream) {
    const float* pd_scores = (const float*)d_in[0];
    const float* pd_bboxes = (const float*)d_in[1];
    const int*   gt_labels = (const int*)d_in[3];
    const float* gt_bboxes = (const float*)d_in[4];
    const float* mask_gt   = (const float*)d_in[5];

    int NA = in_sizes[2] / 2;
    int B  = in_sizes[0] / NA;
    int G  = in_sizes[4] / (B * 4);

    float* out = (float*)d_out;
    float* out_labels = out;                               // (B,NA)
    float* out_bboxes = out_labels + (size_t)B * NA;       // (B,NA,4)
    float* out_scores = out_bboxes + (size_t)B * NA * 4;   // (B,NA,1)
    float* out_fg     = out_scores + (size_t)B * NA;       // (B,NA)

    int BG = B * G;
    size_t BNA = (size_t)B * NA;
    float* thr    = (float*)d_ws;               // BG
    int*   pam    = (int*)(thr + BG);           // BG
    int*   pim    = pam + BG;                   // BG
    int*   ws_tgt = pim + BG;                   // BNA
    float* ws_amv = (float*)(ws_tgt + BNA);     // BNA

    k_thresh<<<dim3(BG), dim3(256), 0, stream>>>(
        pd_scores, pd_bboxes, gt_bboxes, mask_gt, thr, pam, pim, B, G, NA);

    k_assign<<<dim3((NA + 255) / 256, B), dim3(256), 0, stream>>>(
        pd_scores, pd_bboxes, gt_labels, gt_bboxes, mask_gt, thr,
        out_labels, out_bboxes, out_fg, ws_tgt, ws_amv, pam, pim, B, G, NA);

    k_scores<<<dim3((NA + 255) / 256, B), dim3(256), 0, stream>>>(
        ws_tgt, ws_amv, pam, pim, out_labels, out_scores, B, G, NA);
}